// Round 10
// baseline (289.095 us; speedup 1.0000x reference)
//
#include <hip/hip_runtime.h>
#include <stdint.h>

typedef __bf16 bf16;
typedef bf16 bf16x4 __attribute__((ext_vector_type(4)));
typedef bf16 bf16x8 __attribute__((ext_vector_type(8)));
typedef float f32x4 __attribute__((ext_vector_type(4)));

// Inputs fp32, output fp32. Internal: bf16 MFMA, fp32 acc.
// Q is pre-scaled by 0.125*log2(e) in the QKV epilogue so attention softmax
// is exp2(s) with zero extra VALU per element.

// Async global->LDS, 16B/lane; LDS dest = wave-uniform base + lane*16 [m97].
__device__ __forceinline__ void gll16(const bf16* g, const bf16* l) {
  __builtin_amdgcn_global_load_lds(
      (__attribute__((address_space(1))) void*)(g),
      (__attribute__((address_space(3))) void*)(l),
      16, 0, 0);
}

// ---------------- LayerNorm: one block per row of 1024, fp32 in -> bf16 out ----------------
__global__ __launch_bounds__(256) void ln_kernel(
    const float* __restrict__ x, const float* __restrict__ gamma,
    const float* __restrict__ beta, bf16* __restrict__ xn)
{
  __shared__ float red[8];
  const long row = blockIdx.x;
  const int t = threadIdx.x;
  f32x4 f = *(const f32x4*)(x + row * 1024 + t * 4);
  float sum = f[0] + f[1] + f[2] + f[3];
  float sq  = f[0]*f[0] + f[1]*f[1] + f[2]*f[2] + f[3]*f[3];
#pragma unroll
  for (int sh = 1; sh < 64; sh <<= 1) {
    sum += __shfl_xor(sum, sh, 64);
    sq  += __shfl_xor(sq,  sh, 64);
  }
  const int wave = t >> 6, lane = t & 63;
  if (lane == 0) { red[wave] = sum; red[wave + 4] = sq; }
  __syncthreads();
  sum = red[0] + red[1] + red[2] + red[3];
  sq  = red[4] + red[5] + red[6] + red[7];
  const float mu  = sum * (1.0f / 1024.0f);
  const float var = sq * (1.0f / 1024.0f) - mu * mu;
  const float rs  = rsqrtf(var + 1e-5f);
  f32x4 g = *(const f32x4*)(gamma + t * 4);
  f32x4 bb = *(const f32x4*)(beta + t * 4);
  bf16x4 ov;
#pragma unroll
  for (int i = 0; i < 4; i++)
    ov[i] = (bf16)((f[i] - mu) * rs * g[i] + bb[i]);
  *(bf16x4*)(xn + row * 1024 + t * 4) = ov;
}

// ---------------- Weight transposes (both weights, one launch): out[c][r] = (bf16)in[r][c] ----------------
__global__ __launch_bounds__(256) void transpose2_kernel(
    const float* __restrict__ wqkv, bf16* __restrict__ wqkvT,
    const float* __restrict__ wout, bf16* __restrict__ woutT)
{
  __shared__ bf16 tile[32][33];
  const int bx = blockIdx.x;
  const float* in;
  bf16* out;
  int Cc, c0;
  if (bx < 96) { in = wqkv; out = wqkvT; Cc = 3072; c0 = bx * 32; }
  else         { in = wout; out = woutT; Cc = 1024; c0 = (bx - 96) * 32; }
  const int r0 = blockIdx.y * 32;
  const int tx = threadIdx.x & 31, ty = threadIdx.x >> 5;
#pragma unroll
  for (int i = 0; i < 32; i += 8)
    tile[ty + i][tx] = (bf16)in[(long)(r0 + ty + i) * Cc + c0 + tx];
  __syncthreads();
#pragma unroll
  for (int i = 0; i < 32; i += 8)
    out[(long)(c0 + ty + i) * 1024 + r0 + tx] = tile[tx][ty + i];
}

// ---------------- GEMM (out-proj): 128x128 m97 structure, depth-2 counted vmcnt ----------------
// Known-good from R5 (refcheck'd, bank conflicts 0). R10: T1 XCD-affine 1D
// grid (512 = 8x64, bijective): XCD x owns m-panels [8x,8x+8) -> A (att)
// panels 2 MB stay L2-resident across their 8 sharing blocks.
__global__ __launch_bounds__(256, 3) void gemm_bt(
    const bf16* __restrict__ A, const bf16* __restrict__ BT,
    const float* __restrict__ bias, float* __restrict__ C,
    int K, int N)
{
  __shared__ bf16 sA[3][128 * 32];
  __shared__ bf16 sB[3][128 * 32];
  const int t = threadIdx.x;
  const int lane = t & 63;
  const int wave = t >> 6;
  const int wave_u = __builtin_amdgcn_readfirstlane(wave);
  const int quad = lane >> 4;
  const int c16 = lane & 15;
  const int wm = (wave >> 1) * 64;
  const int wn = (wave & 1) * 64;
  // T1 swizzle: i&7 = XCD [m157]; idx = (i&7)*64 + (i>>3); m-panel = idx>>3, n-panel = idx&7
  const int idx = ((blockIdx.x & 7) << 6) + (blockIdx.x >> 3);
  const int m0 = (idx >> 3) * 128;
  const int n0 = (idx & 7) * 128;

  f32x4 acc[4][4] = {};

  const int srow = t >> 2;
  const int scol = (((t & 3) ^ ((t >> 3) & 3)) * 8);
  const bf16* gA = A + (long)(m0 + srow) * K + scol;
  const bf16* gB = BT + (long)(n0 + srow) * K + scol;
  const long rowskip = (long)64 * K;
  const int ksw = (quad ^ ((c16 >> 1) & 3)) * 8;

  const int S = K >> 5;

  auto stage = [&](int b, int kk) {
    const bf16* lA = sA[0] + b * 4096 + wave_u * 512;
    const bf16* lB = sB[0] + b * 4096 + wave_u * 512;
    const int k0 = kk * 32;
    gll16(gA + k0, lA);
    gll16(gA + k0 + rowskip, lA + 2048);
    gll16(gB + k0, lB);
    gll16(gB + k0 + rowskip, lB + 2048);
  };

  stage(0, 0);
  stage(1, 1);

  int bcur = 0;
  for (int s = 0; s < S; s++) {
    if (s + 2 < S) {
      const int bnx = (bcur >= 1) ? bcur - 1 : 2;
      stage(bnx, s + 2);
      asm volatile("s_waitcnt vmcnt(8)" ::: "memory");
    } else if (s + 1 < S) {
      asm volatile("s_waitcnt vmcnt(4)" ::: "memory");
    } else {
      asm volatile("s_waitcnt vmcnt(0)" ::: "memory");
    }
    __builtin_amdgcn_s_barrier();

    const bf16* cA = sA[0] + bcur * 4096;
    const bf16* cB = sB[0] + bcur * 4096;
    bf16x8 af[4], bfr[4];
#pragma unroll
    for (int i = 0; i < 4; i++)
      af[i] = *(const bf16x8*)(cA + (wm + i * 16 + c16) * 32 + ksw);
#pragma unroll
    for (int j = 0; j < 4; j++)
      bfr[j] = *(const bf16x8*)(cB + (wn + j * 16 + c16) * 32 + ksw);
#pragma unroll
    for (int i = 0; i < 4; i++)
#pragma unroll
      for (int j = 0; j < 4; j++)
        acc[i][j] = __builtin_amdgcn_mfma_f32_16x16x32_bf16(af[i], bfr[j], acc[i][j], 0, 0, 0);

    __builtin_amdgcn_s_barrier();
    bcur = (bcur == 2) ? 0 : bcur + 1;
  }

#pragma unroll
  for (int i = 0; i < 4; i++) {
    const int mbase = m0 + wm + i * 16 + quad * 4;
#pragma unroll
    for (int j = 0; j < 4; j++) {
      const int n = n0 + wn + j * 16 + c16;
      const float bv = bias[n];
#pragma unroll
      for (int r = 0; r < 4; r++)
        C[(long)(mbase + r) * N + n] = acc[i][j][r] + bv;
    }
  }
}

// ---------------- QKV GEMM: 256x256 tile, BK=64, 8-phase counted-vmcnt schedule ----------------
// R10: + T1 XCD-affine 1D grid (384 = 8x48, bijective): idx = (i&7)*48+(i>>3),
// m-panel = idx/12, n-panel = idx%12. XCD x owns m-panels [4x,4x+4) -> A
// panels (4 x 512 KB = 2 MB) L2-resident across their 12 sharing blocks.
// Model: staging was L3-latency-bound (~600 cyc > 3-phase lookahead); T1
// converts the A half of staging to L2 latency (m248's stack at K=1024:
// 8ph alone 735 TF, +T1/T2/T5 848 TF).
// R9 phase shape kept (template-exact [m201/m218]): reads at phase top before
// barrier_a; lgkmcnt(0)+sched_barrier(0) after barrier_a (rule #18); vmcnt(6)
// only at end of ph4/ph8. Stage map (iter i): ph1 buf1.Ah1<-2i+1 |
// ph2 buf0.Bh0<-2i+2 | ph3 buf0.Bh1 | ph4 buf0.Ah0 | ph5 buf0.Ah1 |
// ph6 buf1.Bh0<-2i+3 | ph7 buf1.Bh1 | ph8 buf1.Ah0. Tail dup-stages NT-1.
// Granule swizzle g^=(row&7) (rule #21; R5-verified: conflicts 6.29M -> 0).
// Epilogue: QKV scatter (q/k [bh][l][64], v->vt [bh][64][l]); Q scaled.
__global__ __launch_bounds__(512, 2) void gemm_qkv256(
    const bf16* __restrict__ A, const bf16* __restrict__ BT,
    const float* __restrict__ bias,
    bf16* __restrict__ qb, bf16* __restrict__ kb, bf16* __restrict__ vtb,
    int K, int N)
{
  __shared__ bf16 sA[2][2][128 * 64];   // [buf][half][row*64+col]  64 KB
  __shared__ bf16 sB[2][2][128 * 64];   // 64 KB
  const int t = threadIdx.x;
  const int lane = t & 63;
  const int wave = t >> 6;
  const int wave_u = __builtin_amdgcn_readfirstlane(wave);
  const int quad = lane >> 4, c16 = lane & 15;
  const int wM = wave >> 2;             // 0..1  (M half)
  const int wN = wave & 3;              // 0..3  (N quarter)
  const int wm = wM * 128;
  const int wn = wN * 64;
  // T1 swizzle: 384 blocks = 8 XCDs x 48; m-panel = idx/12 (4 per XCD), n-panel = idx%12
  const int idx = ((blockIdx.x & 7) * 48) + (blockIdx.x >> 3);
  const int m0 = (idx / 12) * 256;
  const int n0 = (idx % 12) * 256;
  const int NT = K >> 6;                // K-tiles (16)
  const int NI = K >> 7;                // main iters (8)

  f32x4 acc[8][4] = {};

  // staging: half-tile = 128 rows x 64 cols bf16 = 16 KB = 2 issues x 8 KB
  const int sr = t >> 3;                              // 0..63 row-in-issue
  const int scol = ((t & 7) ^ (sr & 7)) * 8;          // pre-swizzled source granule
  const int fsw = c16 & 7;                            // read-side swizzle key (= row&7)

  auto stageA = [&](int buf, int half, int tile) {
    const long kc = (long)tile * 64;
    const long rb = (long)(m0 + half * 128);
    const bf16* l = &sA[buf][half][0] + wave_u * 512;
    gll16(A + (rb + sr) * K + kc + scol, l);
    gll16(A + (rb + 64 + sr) * K + kc + scol, l + 4096);
  };
  auto stageB = [&](int buf, int half, int tile) {
    const long kc = (long)tile * 64;
    const long rb = (long)(n0 + half * 128);
    const bf16* l = &sB[buf][half][0] + wave_u * 512;
    gll16(BT + (rb + sr) * K + kc + scol, l);
    gll16(BT + (rb + 64 + sr) * K + kc + scol, l + 4096);
  };

  bf16x8 af[4][2], bfr[4][2];
  auto loadA = [&](int b, int mh) {
#pragma unroll
    for (int mi = 0; mi < 4; mi++) {
      const int lr = (mh * 4 + mi) * 16 + c16;
#pragma unroll
      for (int ks = 0; ks < 2; ks++)
        af[mi][ks] = *(const bf16x8*)&sA[b][wM][lr * 64 + (((ks * 4 + quad) ^ fsw) * 8)];
    }
  };
  auto loadB = [&](int b) {
#pragma unroll
    for (int ni = 0; ni < 4; ni++) {
      const int lr = (wN & 1) * 64 + ni * 16 + c16;
#pragma unroll
      for (int ks = 0; ks < 2; ks++)
        bfr[ni][ks] = *(const bf16x8*)&sB[b][wN >> 1][lr * 64 + (((ks * 4 + quad) ^ fsw) * 8)];
    }
  };

#define QUADMFMA(MH, NH)                                                      \
  __builtin_amdgcn_s_setprio(1);                                              \
  _Pragma("unroll")                                                           \
  for (int mi = 0; mi < 4; mi++)                                              \
    _Pragma("unroll")                                                         \
    for (int ni = 0; ni < 2; ni++)                                            \
      _Pragma("unroll")                                                       \
      for (int ks = 0; ks < 2; ks++)                                          \
        acc[(MH)*4 + mi][(NH)*2 + ni] = __builtin_amdgcn_mfma_f32_16x16x32_bf16( \
            af[mi][ks], bfr[(NH)*2 + ni][ks], acc[(MH)*4 + mi][(NH)*2 + ni], 0, 0, 0); \
  __builtin_amdgcn_s_setprio(0);

  // barrier_a + rule-#18 fence: reads retired before MFMA, pinned order
#define PHASE_SYNC                                        \
  __builtin_amdgcn_sched_barrier(0);                      \
  __builtin_amdgcn_s_barrier();                           \
  asm volatile("s_waitcnt lgkmcnt(0)" ::: "memory");      \
  __builtin_amdgcn_sched_barrier(0);

  // prologue: buf0 <- tile 0 (B0,B1,A0,A1), buf1 <- tile 1 (B0,B1,A0). 14 glls.
  stageB(0, 0, 0); stageB(0, 1, 0); stageA(0, 0, 0); stageA(0, 1, 0);
  stageB(1, 0, 1); stageB(1, 1, 1); stageA(1, 0, 1);
  __builtin_amdgcn_sched_barrier(0);
  asm volatile("s_waitcnt vmcnt(6)" ::: "memory");        // buf0 (tile 0) landed
  __builtin_amdgcn_s_barrier();

  for (int i = 0; i < NI; i++) {
    const int tb = (2 * i + 2 < NT) ? 2 * i + 2 : NT - 1;   // buf0's next tile
    const int tc = (2 * i + 3 < NT) ? 2 * i + 3 : NT - 1;   // buf1's next tile

    // ---- phase 1: reads buf0 (A mh0 + all B) || stage buf1.Ah1; MFMA q(0,0)
    loadA(0, 0); loadB(0);
    stageA(1, 1, 2 * i + 1);
    PHASE_SYNC
    QUADMFMA(0, 0)
    __builtin_amdgcn_s_barrier();
    // ---- phase 2: stage buf0.Bh0 (B reads retired in ph1); MFMA q(0,1)
    stageB(0, 0, tb);
    PHASE_SYNC
    QUADMFMA(0, 1)
    __builtin_amdgcn_s_barrier();
    // ---- phase 3: reads buf0 A mh1 || stage buf0.Bh1; MFMA q(1,0)
    loadA(0, 1);
    stageB(0, 1, tb);
    PHASE_SYNC
    QUADMFMA(1, 0)
    __builtin_amdgcn_s_barrier();
    // ---- phase 4: stage buf0.Ah0; vmcnt(6) -> buf1 (tile 2i+1) certified; MFMA q(1,1)
    stageA(0, 0, tb);
    __builtin_amdgcn_sched_barrier(0);
    asm volatile("s_waitcnt vmcnt(6)" ::: "memory");
    __builtin_amdgcn_s_barrier();
    asm volatile("s_waitcnt lgkmcnt(0)" ::: "memory");
    __builtin_amdgcn_sched_barrier(0);
    QUADMFMA(1, 1)
    __builtin_amdgcn_s_barrier();
    // ---- phase 5: reads buf1 (A mh0 + all B) || stage buf0.Ah1; MFMA q(0,0)
    loadA(1, 0); loadB(1);
    stageA(0, 1, tb);
    PHASE_SYNC
    QUADMFMA(0, 0)
    __builtin_amdgcn_s_barrier();
    // ---- phase 6: stage buf1.Bh0; MFMA q(0,1)
    stageB(1, 0, tc);
    PHASE_SYNC
    QUADMFMA(0, 1)
    __builtin_amdgcn_s_barrier();
    // ---- phase 7: reads buf1 A mh1 || stage buf1.Bh1; MFMA q(1,0)
    loadA(1, 1);
    stageB(1, 1, tc);
    PHASE_SYNC
    QUADMFMA(1, 0)
    __builtin_amdgcn_s_barrier();
    // ---- phase 8: stage buf1.Ah0; vmcnt(6) -> buf0 (next tile) certified; MFMA q(1,1)
    stageA(1, 0, tc);
    __builtin_amdgcn_sched_barrier(0);
    asm volatile("s_waitcnt vmcnt(6)" ::: "memory");
    __builtin_amdgcn_s_barrier();
    asm volatile("s_waitcnt lgkmcnt(0)" ::: "memory");
    __builtin_amdgcn_sched_barrier(0);
    QUADMFMA(1, 1)
    __builtin_amdgcn_s_barrier();
  }
  asm volatile("s_waitcnt vmcnt(0)" ::: "memory");          // drain tail dup stages

  // epilogue: QKV scatter. C/D layout: col = c16, row = quad*4 + r [m89/m91].
#pragma unroll
  for (int mi = 0; mi < 8; mi++) {
    const int mbase = m0 + wm + mi * 16 + quad * 4;
#pragma unroll
    for (int ni = 0; ni < 4; ni++) {
      const int n = n0 + wn + ni * 16 + c16;
      const float bv = bias[n];
      const int part = n >> 10;       // 0=Q 1=K 2=V
      const int inner = n & 1023;
      const int h = inner >> 6, d = inner & 63;
#pragma unroll
      for (int r = 0; r < 4; r++) {
        const int m = mbase + r;
        const int b = m >> 11, l = m & 2047;
        const long bh = (long)((b << 4) | h);
        const float v = acc[mi][ni][r] + bv;
        if (part == 0)      qb [(bh * 2048 + l) * 64 + d] = (bf16)(v * 0.18033688f); // 0.125*log2e
        else if (part == 1) kb [(bh * 2048 + l) * 64 + d] = (bf16)v;
        else                vtb[(bh * 64 + d) * 2048 + l] = (bf16)v;
      }
    }
  }
#undef QUADMFMA
#undef PHASE_SYNC
}

// ---------------- Flash attention: swapped QK^T, P in registers, 64 q-rows/wave ----------------
// (unchanged from R6; see R6 notes)
__global__ __launch_bounds__(256, 2) void attn_kernel(
    const bf16* __restrict__ q, const bf16* __restrict__ k,
    const bf16* __restrict__ vt, bf16* __restrict__ att)
{
  __shared__ bf16 sK[128 * 68];
  __shared__ bf16 sVt[64 * 132];

  const int i = blockIdx.x;                 // 0..511
  const int xcd = i & 7;
  const int wi = i >> 3;                    // 0..63
  const int qt = wi & 7;
  const int bh = xcd * 8 + (wi >> 3);
  const int b = bh >> 4, h = bh & 15;
  const int q0 = qt * 256;
  const int t = threadIdx.x;
  const int wave = t >> 6, lane = t & 63;
  const int quad = lane >> 4, c16 = lane & 15;

  const bf16* qp = q + (long)bh * (2048 * 64);
  const bf16* kp = k + (long)bh * (2048 * 64);
  const bf16* vp = vt + (long)bh * (64 * 2048);

  bf16x8 aq[4][2];
#pragma unroll
  for (int m = 0; m < 4; m++) {
    const bf16* qrow = qp + (long)(q0 + wave * 64 + m * 16 + c16) * 64 + quad * 8;
    aq[m][0] = *(const bf16x8*)(qrow);
    aq[m][1] = *(const bf16x8*)(qrow + 32);
  }

  f32x4 o_acc[4][4] = {};
  f32x4 o_sum[4] = {};
  bf16x8 vones;
#pragma unroll
  for (int z = 0; z < 8; z++) vones[z] = (bf16)1.0f;

  const int kr = t >> 3;
  const int kd = (t & 7) * 8;
  const int vr = t >> 4;
  const int vc = t & 15;
  const int vl = vc * 8;
  const int vD0 = (vc >> 2) * 32 + (vc & 1) * 16 + ((vc >> 1) & 1) * 4;

  bf16x8 kreg[4], vreg[4];
#pragma unroll
  for (int it = 0; it < 4; it++) {
    kreg[it] = *(const bf16x8*)(kp + (long)(it * 32 + kr) * 64 + kd);
    vreg[it] = *(const bf16x8*)(vp + (long)(it * 16 + vr) * 2048 + vl);
  }

  for (int kt = 0; kt < 16; kt++) {
    __syncthreads();
#pragma unroll
    for (int it = 0; it < 4; it++)
      *(bf16x8*)&sK[(it * 32 + kr) * 68 + kd] = kreg[it];
#pragma unroll
    for (int it = 0; it < 4; it++) {
      const bf16x8 v = vreg[it];
      const bf16x4 lo = __builtin_shufflevector(v, v, 0, 1, 2, 3);
      const bf16x4 hi = __builtin_shufflevector(v, v, 4, 5, 6, 7);
      bf16* d = &sVt[(it * 16 + vr) * 132 + vD0];
      *(bf16x4*)(d)     = lo;
      *(bf16x4*)(d + 8) = hi;
    }
    __syncthreads();

    const int kvn = ((kt + 1) & 15) * 128;

#pragma unroll
    for (int ks = 0; ks < 4; ks++) {
      bf16x8 ap[4];
#pragma unroll
      for (int e = 0; e < 2; e++) {
        const int jb = ks * 2 + e;
        const bf16x8 bk0 = *(const bf16x8*)&sK[(jb * 16 + c16) * 68 + quad * 8];
        const bf16x8 bk1 = *(const bf16x8*)&sK[(jb * 16 + c16) * 68 + 32 + quad * 8];
#pragma unroll
        for (int m = 0; m < 4; m++) {
          f32x4 z = {};
          z = __builtin_amdgcn_mfma_f32_16x16x32_bf16(bk0, aq[m][0], z, 0, 0, 0);
          z = __builtin_amdgcn_mfma_f32_16x16x32_bf16(bk1, aq[m][1], z, 0, 0, 0);
#pragma unroll
          for (int r = 0; r < 4; r++)
            ap[m][e * 4 + r] = (bf16)__builtin_amdgcn_exp2f(z[r]);
        }
      }
      if (ks == 1) {
#pragma unroll
        for (int it = 0; it < 4; it++)
          kreg[it] = *(const bf16x8*)(kp + (long)(kvn + it * 32 + kr) * 64 + kd);
      }
      if (ks == 2) {
#pragma unroll
        for (int it = 0; it < 4; it++)
          vreg[it] = *(const bf16x8*)(vp + (long)(it * 16 + vr) * 2048 + kvn + vl);
      }
#pragma unroll
      for (int m = 0; m < 4; m++)
        o_sum[m] = __builtin_amdgcn_mfma_f32_16x16x32_bf16(ap[m], vones, o_sum[m], 0, 0, 0);
#pragma unroll
      for (int jd = 0; jd < 4; jd++) {
        const bf16x8 bv = *(const bf16x8*)&sVt[(jd * 16 + c16) * 132 + ks * 32 + quad * 8];
#pragma unroll
        for (int m = 0; m < 4; m++)
          o_acc[m][jd] = __builtin_amdgcn_mfma_f32_16x16x32_bf16(ap[m], bv, o_acc[m][jd], 0, 0, 0);
      }
    }
  }

#pragma unroll
  for (int m = 0; m < 4; m++) {
#pragma unroll
    for (int r = 0; r < 4; r++) {
      const float inv = 1.0f / o_sum[m][r];
      const long rowbase = ((long)b * 2048 + q0 + wave * 64 + m * 16 + quad * 4 + r) * 1024 + h * 64;
#pragma unroll
      for (int jd = 0; jd < 4; jd++)
        att[rowbase + jd * 16 + c16] = (bf16)(o_acc[m][jd][r] * inv);
    }
  }
}

// ---------------- launcher ----------------
extern "C" void kernel_launch(void* const* d_in, const int* in_sizes, int n_in,
                              void* d_out, int out_size, void* d_ws, size_t ws_size,
                              hipStream_t stream) {
  (void)in_sizes; (void)n_in; (void)out_size; (void)ws_size;
  const float* x     = (const float*)d_in[0];
  const float* w_qkv = (const float*)d_in[1];
  const float* b_qkv = (const float*)d_in[2];
  const float* w_out = (const float*)d_in[3];
  const float* b_out = (const float*)d_in[4];
  const float* gamma = (const float*)d_in[5];
  const float* beta  = (const float*)d_in[6];
  float* out = (float*)d_out;
  bf16* ws  = (bf16*)d_ws;

  // ws layout (bf16 elems), total 37.75M elems = 75.5 MB
  bf16* xn    = ws;                    // 8192*1024 (reused as att buffer)
  bf16* wqkvT = ws + 8388608;          // 3072*1024
  bf16* woutT = wqkvT + 3145728;       // 1024*1024
  bf16* qbuf  = woutT + 1048576;       // 8192*1024
  bf16* kbuf  = qbuf + 8388608;        // 8192*1024
  bf16* vtbuf = kbuf + 8388608;        // 8192*1024
  bf16* att   = xn;                    // alias: xn dead after QKV GEMM

  transpose2_kernel<<<dim3(128, 32), 256, 0, stream>>>(w_qkv, wqkvT, w_out, woutT);
  ln_kernel<<<dim3(8192), 256, 0, stream>>>(x, gamma, beta, xn);
  gemm_qkv256<<<dim3(384), 512, 0, stream>>>(
      xn, wqkvT, b_qkv, qbuf, kbuf, vtbuf, 1024, 3072);
  attn_kernel<<<dim3(512), 256, 0, stream>>>(qbuf, kbuf, vtbuf, att);
  gemm_bt<<<dim3(512), 256, 0, stream>>>(
      att, woutT, b_out, out, 1024, 1024);
}

// Round 11
// 268.996 us; speedup vs baseline: 1.0747x; 1.0747x over previous
//
#include <hip/hip_runtime.h>
#include <stdint.h>

typedef __bf16 bf16;
typedef bf16 bf16x4 __attribute__((ext_vector_type(4)));
typedef bf16 bf16x8 __attribute__((ext_vector_type(8)));
typedef float f32x4 __attribute__((ext_vector_type(4)));

// Inputs fp32, output fp32. Internal: bf16 MFMA, fp32 acc.
// Q is pre-scaled by 0.125*log2(e) in the QKV epilogue so attention softmax
// is exp2(s) with zero extra VALU per element.

// Async global->LDS, 16B/lane; LDS dest = wave-uniform base + lane*16 [m97].
__device__ __forceinline__ void gll16(const bf16* g, const bf16* l) {
  __builtin_amdgcn_global_load_lds(
      (__attribute__((address_space(1))) void*)(g),
      (__attribute__((address_space(3))) void*)(l),
      16, 0, 0);
}

// ---------------- LayerNorm: one block per row of 1024, fp32 in -> bf16 out ----------------
__global__ __launch_bounds__(256) void ln_kernel(
    const float* __restrict__ x, const float* __restrict__ gamma,
    const float* __restrict__ beta, bf16* __restrict__ xn)
{
  __shared__ float red[8];
  const long row = blockIdx.x;
  const int t = threadIdx.x;
  f32x4 f = *(const f32x4*)(x + row * 1024 + t * 4);
  float sum = f[0] + f[1] + f[2] + f[3];
  float sq  = f[0]*f[0] + f[1]*f[1] + f[2]*f[2] + f[3]*f[3];
#pragma unroll
  for (int sh = 1; sh < 64; sh <<= 1) {
    sum += __shfl_xor(sum, sh, 64);
    sq  += __shfl_xor(sq,  sh, 64);
  }
  const int wave = t >> 6, lane = t & 63;
  if (lane == 0) { red[wave] = sum; red[wave + 4] = sq; }
  __syncthreads();
  sum = red[0] + red[1] + red[2] + red[3];
  sq  = red[4] + red[5] + red[6] + red[7];
  const float mu  = sum * (1.0f / 1024.0f);
  const float var = sq * (1.0f / 1024.0f) - mu * mu;
  const float rs  = rsqrtf(var + 1e-5f);
  f32x4 g = *(const f32x4*)(gamma + t * 4);
  f32x4 bb = *(const f32x4*)(beta + t * 4);
  bf16x4 ov;
#pragma unroll
  for (int i = 0; i < 4; i++)
    ov[i] = (bf16)((f[i] - mu) * rs * g[i] + bb[i]);
  *(bf16x4*)(xn + row * 1024 + t * 4) = ov;
}

// ---------------- Weight transposes (both weights, one launch): out[c][r] = (bf16)in[r][c] ----------------
__global__ __launch_bounds__(256) void transpose2_kernel(
    const float* __restrict__ wqkv, bf16* __restrict__ wqkvT,
    const float* __restrict__ wout, bf16* __restrict__ woutT)
{
  __shared__ bf16 tile[32][33];
  const int bx = blockIdx.x;
  const float* in;
  bf16* out;
  int Cc, c0;
  if (bx < 96) { in = wqkv; out = wqkvT; Cc = 3072; c0 = bx * 32; }
  else         { in = wout; out = woutT; Cc = 1024; c0 = (bx - 96) * 32; }
  const int r0 = blockIdx.y * 32;
  const int tx = threadIdx.x & 31, ty = threadIdx.x >> 5;
#pragma unroll
  for (int i = 0; i < 32; i += 8)
    tile[ty + i][tx] = (bf16)in[(long)(r0 + ty + i) * Cc + c0 + tx];
  __syncthreads();
#pragma unroll
  for (int i = 0; i < 32; i += 8)
    out[(long)(c0 + ty + i) * 1024 + r0 + tx] = tile[tx][ty + i];
}

// ---------------- GEMM: C[m][n] = sum_k A[m][k] * BT[n][k] + bias[n] ----------------
// R11: HIGH-OCCUPANCY variant. Body = R4's proven 2-buffer ping-pong (one
// __syncthreads per K-step; next tile's 4 glls issued right after the barrier,
// latency overlaps this step's compute; barrier at step s+1 drains them).
// LDS 32 KB + __launch_bounds__(256,4) -> 4-5 blocks/CU = 16-20 waves/CU,
// DOUBLE every prior round (R3-R10 all ran 8-12 waves/CU, and all schedule/
// locality variants were flat within 4% -> hypothesis: TLP starvation [m114],
// not schedule quality). VGPR ~56 << 128 cap. Read/source granule swizzle
// kept from R5 (verified: SQ_LDS_BANK_CONFLICT 6.29M -> 0).
// mode 0: store C [M][N] fp32. mode 1: QKV scatter bf16 (q/k [bh][l][64],
// v->vt [bh][64][l]); Q additionally scaled by 0.125*log2e.
__global__ __launch_bounds__(256, 4) void gemm_bt(
    const bf16* __restrict__ A, const bf16* __restrict__ BT,
    const float* __restrict__ bias, float* __restrict__ C,
    bf16* __restrict__ qb, bf16* __restrict__ kb, bf16* __restrict__ vtb,
    int K, int N, int mode)
{
  __shared__ bf16 sA[2][128 * 32];
  __shared__ bf16 sB[2][128 * 32];
  const int t = threadIdx.x;
  const int lane = t & 63;
  const int wave = t >> 6;
  const int wave_u = __builtin_amdgcn_readfirstlane(wave);
  const int quad = lane >> 4;
  const int c16 = lane & 15;
  const int wm = (wave >> 1) * 64;
  const int wn = (wave & 1) * 64;
  const int m0 = blockIdx.x * 128;
  const int n0 = blockIdx.y * 128;

  f32x4 acc[4][4] = {};

  const int srow = t >> 2;                               // 0..63
  const int scol = (((t & 3) ^ ((t >> 3) & 3)) * 8);     // pre-swizzled source granule
  const bf16* gA = A + (long)(m0 + srow) * K + scol;
  const bf16* gB = BT + (long)(n0 + srow) * K + scol;
  const long rowskip = (long)64 * K;
  const int ksw = (quad ^ ((c16 >> 1) & 3)) * 8;         // swizzled read offset (elems)

  const int S = K >> 5;

  auto stage = [&](int b, int kk) {
    const bf16* lA = sA[0] + b * 4096 + wave_u * 512;
    const bf16* lB = sB[0] + b * 4096 + wave_u * 512;
    const int k0 = kk * 32;
    gll16(gA + k0, lA);
    gll16(gA + k0 + rowskip, lA + 2048);
    gll16(gB + k0, lB);
    gll16(gB + k0 + rowskip, lB + 2048);
  };

  // prologue: stage step 0 into buffer 0
  stage(0, 0);

  int cur = 0;
  for (int s = 0; s < S; s++) {
    __syncthreads();                 // stage(s) visible; prev reads of buf[cur^1] done
    if (s + 1 < S)
      stage(cur ^ 1, s + 1);         // in flight across this step's compute
    const bf16* cA = sA[0] + cur * 4096;
    const bf16* cB = sB[0] + cur * 4096;
    bf16x8 af[4], bfr[4];
#pragma unroll
    for (int i = 0; i < 4; i++)
      af[i] = *(const bf16x8*)(cA + (wm + i * 16 + c16) * 32 + ksw);
#pragma unroll
    for (int j = 0; j < 4; j++)
      bfr[j] = *(const bf16x8*)(cB + (wn + j * 16 + c16) * 32 + ksw);
#pragma unroll
    for (int i = 0; i < 4; i++)
#pragma unroll
      for (int j = 0; j < 4; j++)
        acc[i][j] = __builtin_amdgcn_mfma_f32_16x16x32_bf16(af[i], bfr[j], acc[i][j], 0, 0, 0);
    cur ^= 1;
  }

  // C/D layout: col = lane&15, row = quad*4 + reg   [verified m89/m91]
#pragma unroll
  for (int i = 0; i < 4; i++) {
    const int mbase = m0 + wm + i * 16 + quad * 4;
#pragma unroll
    for (int j = 0; j < 4; j++) {
      const int n = n0 + wn + j * 16 + c16;
      const float bv = bias[n];
      if (mode == 0) {
#pragma unroll
        for (int r = 0; r < 4; r++)
          C[(long)(mbase + r) * N + n] = acc[i][j][r] + bv;
      } else {
        const int part = n >> 10;       // 0=Q 1=K 2=V
        const int inner = n & 1023;
        const int h = inner >> 6, d = inner & 63;
#pragma unroll
        for (int r = 0; r < 4; r++) {
          const int m = mbase + r;
          const int b = m >> 11, l = m & 2047;
          const long bh = (long)((b << 4) | h);
          const float v = acc[i][j][r] + bv;
          if (part == 0)      qb [(bh * 2048 + l) * 64 + d] = (bf16)(v * 0.18033688f); // 0.125*log2e
          else if (part == 1) kb [(bh * 2048 + l) * 64 + d] = (bf16)v;
          else                vtb[(bh * 64 + d) * 2048 + l] = (bf16)v;
        }
      }
    }
  }
}

// ---------------- Flash attention: swapped QK^T, P in registers, 64 q-rows/wave ----------------
// (unchanged from R6; see R6 notes)
__global__ __launch_bounds__(256, 2) void attn_kernel(
    const bf16* __restrict__ q, const bf16* __restrict__ k,
    const bf16* __restrict__ vt, bf16* __restrict__ att)
{
  __shared__ bf16 sK[128 * 68];
  __shared__ bf16 sVt[64 * 132];

  const int i = blockIdx.x;                 // 0..511
  const int xcd = i & 7;
  const int wi = i >> 3;                    // 0..63
  const int qt = wi & 7;
  const int bh = xcd * 8 + (wi >> 3);
  const int b = bh >> 4, h = bh & 15;
  const int q0 = qt * 256;
  const int t = threadIdx.x;
  const int wave = t >> 6, lane = t & 63;
  const int quad = lane >> 4, c16 = lane & 15;

  const bf16* qp = q + (long)bh * (2048 * 64);
  const bf16* kp = k + (long)bh * (2048 * 64);
  const bf16* vp = vt + (long)bh * (64 * 2048);

  bf16x8 aq[4][2];
#pragma unroll
  for (int m = 0; m < 4; m++) {
    const bf16* qrow = qp + (long)(q0 + wave * 64 + m * 16 + c16) * 64 + quad * 8;
    aq[m][0] = *(const bf16x8*)(qrow);
    aq[m][1] = *(const bf16x8*)(qrow + 32);
  }

  f32x4 o_acc[4][4] = {};
  f32x4 o_sum[4] = {};
  bf16x8 vones;
#pragma unroll
  for (int z = 0; z < 8; z++) vones[z] = (bf16)1.0f;

  const int kr = t >> 3;
  const int kd = (t & 7) * 8;
  const int vr = t >> 4;
  const int vc = t & 15;
  const int vl = vc * 8;
  const int vD0 = (vc >> 2) * 32 + (vc & 1) * 16 + ((vc >> 1) & 1) * 4;

  bf16x8 kreg[4], vreg[4];
#pragma unroll
  for (int it = 0; it < 4; it++) {
    kreg[it] = *(const bf16x8*)(kp + (long)(it * 32 + kr) * 64 + kd);
    vreg[it] = *(const bf16x8*)(vp + (long)(it * 16 + vr) * 2048 + vl);
  }

  for (int kt = 0; kt < 16; kt++) {
    __syncthreads();
#pragma unroll
    for (int it = 0; it < 4; it++)
      *(bf16x8*)&sK[(it * 32 + kr) * 68 + kd] = kreg[it];
#pragma unroll
    for (int it = 0; it < 4; it++) {
      const bf16x8 v = vreg[it];
      const bf16x4 lo = __builtin_shufflevector(v, v, 0, 1, 2, 3);
      const bf16x4 hi = __builtin_shufflevector(v, v, 4, 5, 6, 7);
      bf16* d = &sVt[(it * 16 + vr) * 132 + vD0];
      *(bf16x4*)(d)     = lo;
      *(bf16x4*)(d + 8) = hi;
    }
    __syncthreads();

    const int kvn = ((kt + 1) & 15) * 128;

#pragma unroll
    for (int ks = 0; ks < 4; ks++) {
      bf16x8 ap[4];
#pragma unroll
      for (int e = 0; e < 2; e++) {
        const int jb = ks * 2 + e;
        const bf16x8 bk0 = *(const bf16x8*)&sK[(jb * 16 + c16) * 68 + quad * 8];
        const bf16x8 bk1 = *(const bf16x8*)&sK[(jb * 16 + c16) * 68 + 32 + quad * 8];
#pragma unroll
        for (int m = 0; m < 4; m++) {
          f32x4 z = {};
          z = __builtin_amdgcn_mfma_f32_16x16x32_bf16(bk0, aq[m][0], z, 0, 0, 0);
          z = __builtin_amdgcn_mfma_f32_16x16x32_bf16(bk1, aq[m][1], z, 0, 0, 0);
#pragma unroll
          for (int r = 0; r < 4; r++)
            ap[m][e * 4 + r] = (bf16)__builtin_amdgcn_exp2f(z[r]);
        }
      }
      if (ks == 1) {
#pragma unroll
        for (int it = 0; it < 4; it++)
          kreg[it] = *(const bf16x8*)(kp + (long)(kvn + it * 32 + kr) * 64 + kd);
      }
      if (ks == 2) {
#pragma unroll
        for (int it = 0; it < 4; it++)
          vreg[it] = *(const bf16x8*)(vp + (long)(it * 16 + vr) * 2048 + kvn + vl);
      }
#pragma unroll
      for (int m = 0; m < 4; m++)
        o_sum[m] = __builtin_amdgcn_mfma_f32_16x16x32_bf16(ap[m], vones, o_sum[m], 0, 0, 0);
#pragma unroll
      for (int jd = 0; jd < 4; jd++) {
        const bf16x8 bv = *(const bf16x8*)&sVt[(jd * 16 + c16) * 132 + ks * 32 + quad * 8];
#pragma unroll
        for (int m = 0; m < 4; m++)
          o_acc[m][jd] = __builtin_amdgcn_mfma_f32_16x16x32_bf16(ap[m], bv, o_acc[m][jd], 0, 0, 0);
      }
    }
  }

#pragma unroll
  for (int m = 0; m < 4; m++) {
#pragma unroll
    for (int r = 0; r < 4; r++) {
      const float inv = 1.0f / o_sum[m][r];
      const long rowbase = ((long)b * 2048 + q0 + wave * 64 + m * 16 + quad * 4 + r) * 1024 + h * 64;
#pragma unroll
      for (int jd = 0; jd < 4; jd++)
        att[rowbase + jd * 16 + c16] = (bf16)(o_acc[m][jd][r] * inv);
    }
  }
}

// ---------------- launcher ----------------
extern "C" void kernel_launch(void* const* d_in, const int* in_sizes, int n_in,
                              void* d_out, int out_size, void* d_ws, size_t ws_size,
                              hipStream_t stream) {
  (void)in_sizes; (void)n_in; (void)out_size; (void)ws_size;
  const float* x     = (const float*)d_in[0];
  const float* w_qkv = (const float*)d_in[1];
  const float* b_qkv = (const float*)d_in[2];
  const float* w_out = (const float*)d_in[3];
  const float* b_out = (const float*)d_in[4];
  const float* gamma = (const float*)d_in[5];
  const float* beta  = (const float*)d_in[6];
  float* out = (float*)d_out;
  bf16* ws  = (bf16*)d_ws;

  // ws layout (bf16 elems), total 37.75M elems = 75.5 MB
  bf16* xn    = ws;                    // 8192*1024 (reused as att buffer)
  bf16* wqkvT = ws + 8388608;          // 3072*1024
  bf16* woutT = wqkvT + 3145728;       // 1024*1024
  bf16* qbuf  = woutT + 1048576;       // 8192*1024
  bf16* kbuf  = qbuf + 8388608;        // 8192*1024
  bf16* vtbuf = kbuf + 8388608;        // 8192*1024
  bf16* att   = xn;                    // alias: xn dead after QKV GEMM

  transpose2_kernel<<<dim3(128, 32), 256, 0, stream>>>(w_qkv, wqkvT, w_out, woutT);
  ln_kernel<<<dim3(8192), 256, 0, stream>>>(x, gamma, beta, xn);
  gemm_bt<<<dim3(8192 / 128, 3072 / 128), 256, 0, stream>>>(
      xn, wqkvT, b_qkv, (float*)nullptr, qbuf, kbuf, vtbuf, 1024, 3072, 1);
  attn_kernel<<<dim3(512), 256, 0, stream>>>(qbuf, kbuf, vtbuf, att);
  gemm_bt<<<dim3(8192 / 128, 1024 / 128), 256, 0, stream>>>(
      att, woutT, b_out, out, (bf16*)nullptr, (bf16*)nullptr, (bf16*)nullptr, 1024, 1024, 0);
}